// Round 1
// baseline (147.580 us; speedup 1.0000x reference)
//
#include <hip/hip_runtime.h>
#include <hip/hip_bf16.h>

typedef __attribute__((ext_vector_type(8))) short short8;
typedef __attribute__((ext_vector_type(4))) short bf16x4;
typedef __attribute__((ext_vector_type(4))) float f32x4;

#define TT 2048   // sequence length
#define DM 1024   // model dim
#define NH 16     // query heads
#define NKV 4     // kv heads
#define HD 64     // head dim

#define MFMA32(a,b,c) __builtin_amdgcn_mfma_f32_16x16x32_bf16(a,b,c,0,0,0)
#define MFMA16(a,b,c) __builtin_amdgcn_mfma_f32_16x16x16bf16_1k(a,b,c,0,0,0)

__device__ __forceinline__ unsigned short f2bf(float x){
  unsigned int u = __float_as_uint(x);
  u += 0x7fffu + ((u >> 16) & 1u);   // RNE
  return (unsigned short)(u >> 16);
}
// packed 2xfp32 -> 2xbf16 (v_cvt_pk_bf16_f32 on gfx950)
__device__ __forceinline__ unsigned int pkbf2(float x, float y){
  union { __hip_bfloat162 h; unsigned int u; } t;
  t.h = __float22bfloat162_rn(make_float2(x, y));
  return t.u;
}
// async global->LDS, 16B/lane; lds dest = wave-uniform base + lane*16
__device__ __forceinline__ void gl_lds16(const unsigned short* g, unsigned short* l){
  __builtin_amdgcn_global_load_lds(
      (__attribute__((address_space(1))) void*)g,
      (__attribute__((address_space(3))) void*)l, 16, 0, 0);
}

// ---------------- 1. x + weights fp32 -> bf16 ----------------
__global__ __launch_bounds__(256) void convertw_kernel(
    const float* __restrict__ x,
    const float* __restrict__ qw, const float* __restrict__ kw,
    const float* __restrict__ vw, const float* __restrict__ ow,
    unsigned short* __restrict__ xb,
    unsigned short* __restrict__ wqkv, unsigned short* __restrict__ owb){
  long v = (long)blockIdx.x * 256 + threadIdx.x;
  const float* src; unsigned short* dst; long base;
  if      (v < 524288) { src = x;  dst = xb;             base = v; }
  else if (v < 786432) { src = qw; dst = wqkv;           base = v - 524288; }
  else if (v < 851968) { src = kw; dst = wqkv + 1048576; base = v - 786432; }
  else if (v < 917504) { src = vw; dst = wqkv + 1310720; base = v - 851968; }
  else                 { src = ow; dst = owb;            base = v - 917504; }
  f32x4 d = *(const f32x4*)(src + base * 4);
  uint2 pk = { pkbf2(d[0], d[1]), pkbf2(d[2], d[3]) };
  *(uint2*)(dst + base * 4) = pk;
}

// ---------------- 2. QKV GEMM (2-phase double-buffered async LDS staging)
//                    + fused RMSNorm/RoPE/q0k0/Vtrans ----
// grid dim3(24, 32): x = head-block (0..15 q | 16..19 k | 20..23 v), y = 64-row t-tile
// K-loop: BK=64 as two [64][32]-short halves, DOUBLE-buffered: stage(next) issued
// before compute(cur); single vmcnt-drain barrier per K-step (T3-minimum recipe).
// Ct epilogue buffer aliases the As/Bs staging space (live only after K-loop).
__global__ __launch_bounds__(256) void gemm1_fused(
    const unsigned short* __restrict__ xb, const unsigned short* __restrict__ wqkv,
    unsigned short* __restrict__ qb, unsigned short* __restrict__ kb,
    unsigned short* __restrict__ vt,
    float* __restrict__ q0, float* __restrict__ k0,
    float* __restrict__ bpart, const float* __restrict__ curv){
  // [buf][half][64][32] shorts for A and B: 2*2*2048 shorts = 8 KB*2 each -> 32 KB
  __shared__ __align__(16) unsigned short AB[2 * 8192];
  __shared__ float bsum;
  unsigned short* As = AB;            // 16 KB
  unsigned short* Bs = AB + 8192;     // 16 KB
  float* Ct = (float*)AB;             // 64*65 f32 = 16.6 KB, aliases As/Bs post-loop
  const int tid = threadIdx.x, lane = tid & 63, wave = tid >> 6;
  const int hIdx = blockIdx.x;
  const int bm = blockIdx.y * 64, bn = hIdx * 64;
  const int wm = (wave >> 1) * 32, wn = (wave & 1) * 32;
  const int ml = lane & 15, quad = lane >> 4;
  if (tid == 0) bsum = 0.f;
  f32x4 acc[2][2];
  const f32x4 z = {0.f, 0.f, 0.f, 0.f};
  acc[0][0] = z; acc[0][1] = z; acc[1][0] = z; acc[1][1] = z;

  // staging: wave w covers rows w*16..w*16+15 of a [64][32] half;
  // lane i -> row w*16 + i/4, col (i&3)*8 shorts (16B)
  const int srow = wave * 16 + (lane >> 2), scol = (lane & 3) * 8;
  const unsigned short* Ag = xb   + (long)(bm + srow) * 1024 + scol;
  const unsigned short* Bg = wqkv + (long)(bn + srow) * 1024 + scol;

#define G1_STAGE(nb, ko)                                           \
  do {                                                             \
    gl_lds16(Ag + (ko),      As + (nb) * 4096 + wave * 512);       \
    gl_lds16(Ag + (ko) + 32, As + (nb) * 4096 + 2048 + wave * 512);\
    gl_lds16(Bg + (ko),      Bs + (nb) * 4096 + wave * 512);       \
    gl_lds16(Bg + (ko) + 32, Bs + (nb) * 4096 + 2048 + wave * 512);\
  } while (0)

#define G1_COMPUTE(b)                                                   \
  do {                                                                  \
    _Pragma("unroll")                                                   \
    for (int half = 0; half < 2; half++){                               \
      const unsigned short* Ah = As + (b) * 4096 + half * 2048;         \
      const unsigned short* Bh = Bs + (b) * 4096 + half * 2048;         \
      short8 a0f = *(const short8*)&Ah[(wm + ml) * 32 + quad * 8];      \
      short8 a1f = *(const short8*)&Ah[(wm + 16 + ml) * 32 + quad * 8]; \
      short8 b0f = *(const short8*)&Bh[(wn + ml) * 32 + quad * 8];      \
      short8 b1f = *(const short8*)&Bh[(wn + 16 + ml) * 32 + quad * 8]; \
      acc[0][0] = MFMA32(a0f, b0f, acc[0][0]);                          \
      acc[0][1] = MFMA32(a0f, b1f, acc[0][1]);                          \
      acc[1][0] = MFMA32(a1f, b0f, acc[1][0]);                          \
      acc[1][1] = MFMA32(a1f, b1f, acc[1][1]);                          \
    }                                                                   \
  } while (0)

  // prologue: stage K-step 0 into buf 0; barrier drains vmcnt
  G1_STAGE(0, 0);
  __syncthreads();
  // 2-phase main loop, unrolled x2 so buffer index is compile-time static
  for (int kk = 0; kk < 1024; kk += 128){
    G1_STAGE(1, kk + 64);            // issue next-tile loads (in flight over compute)
    G1_COMPUTE(0);
    __syncthreads();                 // vmcnt(0)+barrier: next buf ready, cur buf free
    if (kk + 128 < 1024) G1_STAGE(0, kk + 128);
    G1_COMPUTE(1);
    __syncthreads();
  }
#undef G1_STAGE
#undef G1_COMPUTE

  // K-loop done; all waves past final barrier -> safe to overwrite AB with Ct
#pragma unroll
  for (int i = 0; i < 2; i++)
#pragma unroll
    for (int j = 0; j < 2; j++)
#pragma unroll
      for (int r = 0; r < 4; r++)
        Ct[(wm + i * 16 + quad * 4 + r) * 65 + wn + j * 16 + ml] = acc[i][j][r];
  __syncthreads();

  if (hIdx < 20){
    // RMSNorm + RoPE + q0/k0 (+ spatial partial for q). lane = head-dim d.
    const bool isq = hIdx < 16;
    const int h = isq ? hIdx : hIdx - 16;
    const float c = curv[0];
    unsigned short* ob = isq ? qb : kb;
    float* o0 = isq ? q0 : k0;
#pragma unroll 1
    for (int rr = 0; rr < 16; rr++){
      const int row = wave * 16 + rr;
      const int t = bm + row;
      float val = Ct[row * 65 + lane];
      float ss = val * val;
#pragma unroll
      for (int off = 1; off < 64; off <<= 1) ss += __shfl_xor(ss, off);
      float scale = __builtin_amdgcn_rsqf(ss * (1.f / 64.f) + 1e-6f);
      float xn = val * scale;
      float other = __shfl_xor(xn, 32);
      int fi = lane & 31;
      float ang = (float)t * __builtin_amdgcn_exp2f((float)fi * (-13.287712379549449f / 32.f));
      float sn, cs; __sincosf(ang, &sn, &cs);
      float outv = (lane < 32) ? (xn * cs + other * sn) : (xn * cs - other * sn);
      ob[((long)h * TT + t) * 64 + lane] = f2bf(outv);
      if (lane == 0){
        float sq = ss * scale * scale;      // |normed|^2, rope preserves norm
        o0[h * TT + t] = __builtin_amdgcn_sqrtf(1.f / c + sq);
        if (isq) atomicAdd(&bsum, __builtin_amdgcn_sqrtf(sq));
      }
    }
  } else {
    // V: bf16 + write in PV-fragment order vt2[hk][tile][d][key16]
    const int hk = hIdx - 20;
    const int d = tid >> 2, tseg = (tid & 3) * 16;
    uint4 w0, w1;
    w0.x = pkbf2(Ct[(tseg + 0) * 65 + d], Ct[(tseg + 1) * 65 + d]);
    w0.y = pkbf2(Ct[(tseg + 2) * 65 + d], Ct[(tseg + 3) * 65 + d]);
    w0.z = pkbf2(Ct[(tseg + 4) * 65 + d], Ct[(tseg + 5) * 65 + d]);
    w0.w = pkbf2(Ct[(tseg + 6) * 65 + d], Ct[(tseg + 7) * 65 + d]);
    w1.x = pkbf2(Ct[(tseg + 8) * 65 + d], Ct[(tseg + 9) * 65 + d]);
    w1.y = pkbf2(Ct[(tseg +10) * 65 + d], Ct[(tseg +11) * 65 + d]);
    w1.z = pkbf2(Ct[(tseg +12) * 65 + d], Ct[(tseg +13) * 65 + d]);
    w1.w = pkbf2(Ct[(tseg +14) * 65 + d], Ct[(tseg +15) * 65 + d]);
    const int tile = (bm + tseg) >> 4;
    unsigned short* dst = vt + ((long)(hk * 128 + tile) * 64 + d) * 16;
    *(uint4*)dst = w0;
    *(uint4*)(dst + 8) = w1;
  }
  __syncthreads();
  if (tid == 0) bpart[blockIdx.y * 24 + hIdx] = bsum;
}

// ---------------- 3. head-pair-fused hyperbolic causal attention (unchanged) -------
__global__ __launch_bounds__(256, 3) void attn_kernel(
    const unsigned short* __restrict__ qb_, const unsigned short* __restrict__ kb_,
    const unsigned short* __restrict__ vt_,
    const float* __restrict__ q0_, const float* __restrict__ k0_,
    const float* __restrict__ temp, const float* __restrict__ curv,
    unsigned short* __restrict__ attn_out,
    const float* __restrict__ bpart, float* __restrict__ out_scalar){
  __shared__ float lds[8 * 1104];    // regions: wave (head0), 4+wave (head1)
  const int tid = threadIdx.x, lane = tid & 63, wave = tid >> 6;
  const int qt  = 127 - (blockIdx.x >> 3);     // longest-first
  const int sub = blockIdx.x & 7;
  const int kvh = sub >> 1, hp = sub & 1;
  const int h0 = kvh * 4 + hp * 2, h1 = h0 + 1;
  const int i0 = qt * 16;
  const int ml = lane & 15, quad = lane >> 4;
  const float c = curv[0];
  const float rsc = __builtin_amdgcn_rsqf(c);
  const float fac0 = -rsc / temp[h0];
  const float fac1 = -rsc / temp[h1];
  const f32x4 z = {0.f, 0.f, 0.f, 0.f};
  const unsigned short* kh = kb_ + (long)kvh * TT * 64;
  const unsigned short* vh = vt_ + (long)kvh * 128 * 1024;   // [tile][d][key16]
  const float* k0h = k0_ + kvh * TT;

  short8 qa0 = *(const short8*)&qb_[((long)h0 * TT + i0 + ml) * 64 + quad * 8];
  short8 qa1 = *(const short8*)&qb_[((long)h0 * TT + i0 + ml) * 64 + 32 + quad * 8];
  short8 qb0 = *(const short8*)&qb_[((long)h1 * TT + i0 + ml) * 64 + quad * 8];
  short8 qb1 = *(const short8*)&qb_[((long)h1 * TT + i0 + ml) * 64 + 32 + quad * 8];
  const float q0c0 = c * q0_[h0 * TT + i0 + ml];   // per-lane: q = i0+ml
  const float q0c1 = c * q0_[h1 * TT + i0 + ml];
  const int rowq = i0 + ml;

  f32x4 o0[4], o1[4];
#pragma unroll
  for (int dt = 0; dt < 4; dt++){ o0[dt] = z; o1[dt] = z; }
  float l0 = 0.f, l1 = 0.f;

  const int nt = (i0 + 47) >> 5;   // 32-key tiles

#pragma unroll 1
  for (int t = wave; t < nt; t += 4){
    const int j0 = t << 5;
    const unsigned short* kp = kh + (long)j0 * 64;
    short8 ka0 = *(const short8*)(kp + ml * 64 + quad * 8);
    short8 ka1 = *(const short8*)(kp + ml * 64 + 32 + quad * 8);
    short8 kc0 = *(const short8*)(kp + (16 + ml) * 64 + quad * 8);
    short8 kc1 = *(const short8*)(kp + (16 + ml) * 64 + 32 + quad * 8);
    f32x4 k0a = *(const f32x4*)(k0h + j0 + quad * 4);
    f32x4 k0b = *(const f32x4*)(k0h + j0 + 16 + quad * 4);
    const unsigned short* vpa = vh + (long)(j0 >> 4) * 1024;
    bf16x4 vfa0 = *(const bf16x4*)(vpa + ( 0 + ml) * 16 + quad * 4);
    bf16x4 vfa1 = *(const bf16x4*)(vpa + (16 + ml) * 16 + quad * 4);
    bf16x4 vfa2 = *(const bf16x4*)(vpa + (32 + ml) * 16 + quad * 4);
    bf16x4 vfa3 = *(const bf16x4*)(vpa + (48 + ml) * 16 + quad * 4);
    bf16x4 vfb0 = *(const bf16x4*)(vpa + 1024 + ( 0 + ml) * 16 + quad * 4);
    bf16x4 vfb1 = *(const bf16x4*)(vpa + 1024 + (16 + ml) * 16 + quad * 4);
    bf16x4 vfb2 = *(const bf16x4*)(vpa + 1024 + (32 + ml) * 16 + quad * 4);
    bf16x4 vfb3 = *(const bf16x4*)(vpa + 1024 + (48 + ml) * 16 + quad * 4);

    const int keyb = j0 + quad * 4;
    const bool nm = (j0 + 31 > i0);
    // ---- head 0 ----
    {
      f32x4 s0 = z, s1 = z;
      s0 = MFMA32(ka0, qa0, s0);
      s0 = MFMA32(ka1, qa1, s0);
      s1 = MFMA32(kc0, qa0, s1);
      s1 = MFMA32(kc1, qa1, s1);
      float p0[4], p1[4];
#pragma unroll
      for (int r = 0; r < 4; r++){
        float argA = fmaxf(__builtin_fmaf(-c, s0[r], q0c0 * k0a[r]), 1.00001f);
        float wA   = argA + __builtin_amdgcn_sqrtf(__builtin_fmaf(argA, argA, -1.f));
        float pA   = __builtin_amdgcn_exp2f(fac0 * __builtin_amdgcn_logf(wA));
        float argB = fmaxf(__builtin_fmaf(-c, s1[r], q0c0 * k0b[r]), 1.00001f);
        float wB   = argB + __builtin_amdgcn_sqrtf(__builtin_fmaf(argB, argB, -1.f));
        float pB   = __builtin_amdgcn_exp2f(fac0 * __builtin_amdgcn_logf(wB));
        if (nm){
          if (keyb + r > rowq)      pA = 0.f;
          if (keyb + 16 + r > rowq) pB = 0.f;
        }
        p0[r] = pA; p1[r] = pB;
        l0 += pA + pB;
      }
      uint2 pua = { pkbf2(p0[0], p0[1]), pkbf2(p0[2], p0[3]) };
      uint2 pub = { pkbf2(p1[0], p1[1]), pkbf2(p1[2], p1[3]) };
      bf16x4 pfa = *(bf16x4*)&pua;
      bf16x4 pfb = *(bf16x4*)&pub;
      o0[0] = MFMA16(vfa0, pfa, o0[0]);
      o0[1] = MFMA16(vfa1, pfa, o0[1]);
      o0[2] = MFMA16(vfa2, pfa, o0[2]);
      o0[3] = MFMA16(vfa3, pfa, o0[3]);
      o0[0] = MFMA16(vfb0, pfb, o0[0]);
      o0[1] = MFMA16(vfb1, pfb, o0[1]);
      o0[2] = MFMA16(vfb2, pfb, o0[2]);
      o0[3] = MFMA16(vfb3, pfb, o0[3]);
    }
    // ---- head 1 (same K/V tile) ----
    {
      f32x4 s0 = z, s1 = z;
      s0 = MFMA32(ka0, qb0, s0);
      s0 = MFMA32(ka1, qb1, s0);
      s1 = MFMA32(kc0, qb0, s1);
      s1 = MFMA32(kc1, qb1, s1);
      float p0[4], p1[4];
#pragma unroll
      for (int r = 0; r < 4; r++){
        float argA = fmaxf(__builtin_fmaf(-c, s0[r], q0c1 * k0a[r]), 1.00001f);
        float wA   = argA + __builtin_amdgcn_sqrtf(__builtin_fmaf(argA, argA, -1.f));
        float pA   = __builtin_amdgcn_exp2f(fac1 * __builtin_amdgcn_logf(wA));
        float argB = fmaxf(__builtin_fmaf(-c, s1[r], q0c1 * k0b[r]), 1.00001f);
        float wB   = argB + __builtin_amdgcn_sqrtf(__builtin_fmaf(argB, argB, -1.f));
        float pB   = __builtin_amdgcn_exp2f(fac1 * __builtin_amdgcn_logf(wB));
        if (nm){
          if (keyb + r > rowq)      pA = 0.f;
          if (keyb + 16 + r > rowq) pB = 0.f;
        }
        p0[r] = pA; p1[r] = pB;
        l1 += pA + pB;
      }
      uint2 pua = { pkbf2(p0[0], p0[1]), pkbf2(p0[2], p0[3]) };
      uint2 pub = { pkbf2(p1[0], p1[1]), pkbf2(p1[2], p1[3]) };
      bf16x4 pfa = *(bf16x4*)&pua;
      bf16x4 pfb = *(bf16x4*)&pub;
      o1[0] = MFMA16(vfa0, pfa, o1[0]);
      o1[1] = MFMA16(vfa1, pfa, o1[1]);
      o1[2] = MFMA16(vfa2, pfa, o1[2]);
      o1[3] = MFMA16(vfa3, pfa, o1[3]);
      o1[0] = MFMA16(vfb0, pfb, o1[0]);
      o1[1] = MFMA16(vfb1, pfb, o1[1]);
      o1[2] = MFMA16(vfb2, pfb, o1[2]);
      o1[3] = MFMA16(vfb3, pfb, o1[3]);
    }
  }
  // l across quads (keys split over quads/regs; q=ml fixed)
  l0 += __shfl_xor(l0, 16); l0 += __shfl_xor(l0, 32);
  l1 += __shfl_xor(l1, 16); l1 += __shfl_xor(l1, 32);
  // publish wave partials: O^T reg r -> d = dt*16+quad*4+r at q=ml
  {
    float* w0 = lds + wave * 1104;
    float* w1 = lds + (4 + wave) * 1104;
#pragma unroll
    for (int dt = 0; dt < 4; dt++){
      *(f32x4*)&w0[ml * 68 + dt * 16 + quad * 4] = o0[dt];
      *(f32x4*)&w1[ml * 68 + dt * 16 + quad * 4] = o1[dt];
    }
    if (quad == 0){ w0[1088 + ml] = l0; w1[1088 + ml] = l1; }
  }
  __syncthreads();
  // merge 4 waves per head: thread -> (row = tid>>4, 4 d's)
  {
    const int row = tid >> 4, c0 = (tid & 15) * 4;
#pragma unroll 1
    for (int hb = 0; hb < 2; hb++){
      const float* base = lds + hb * 4 * 1104;
      float L = 0.f; f32x4 s = z;
#pragma unroll
      for (int w = 0; w < 4; w++){
        const float* rg = base + w * 1104;
        L += rg[1088 + row];
        f32x4 t2 = *(const f32x4*)&rg[row * 68 + c0];
        s[0] += t2[0]; s[1] += t2[1]; s[2] += t2[2]; s[3] += t2[3];
      }
      float invL = __builtin_amdgcn_rcpf(L);
      const int h = hb ? h1 : h0;
      uint2 o = { pkbf2(s[0] * invL, s[1] * invL), pkbf2(s[2] * invL, s[3] * invL) };
      *(uint2*)&attn_out[(long)(i0 + row) * 1024 + h * 64 + c0] = o;
    }
  }
  // fused spatial_norm finalize
  if (blockIdx.x == 0 && tid < 64){
    float s = 0.f;
    for (int i = lane; i < 768; i += 64) s += bpart[i];
#pragma unroll
    for (int off = 1; off < 64; off <<= 1) s += __shfl_xor(s, off);
    if (lane == 0) out_scalar[0] = s * (1.f / 32768.f);
  }
}

// ---------------- 4. O-proj GEMM (2-phase double-buffered staging): out = attn x owb^T
__global__ __launch_bounds__(256) void gemm2_kernel(
    const unsigned short* __restrict__ A, const unsigned short* __restrict__ B,
    float* __restrict__ C){
  __shared__ __align__(16) unsigned short As[2 * 4096];  // [buf][half][64][32] 16 KB
  __shared__ __align__(16) unsigned short Bs[2 * 4096];
  const int tid = threadIdx.x, lane = tid & 63, wave = tid >> 6;
  const int bm = blockIdx.y * 64, bn = blockIdx.x * 64;
  const int wm = (wave >> 1) * 32, wn = (wave & 1) * 32;
  const int ml = lane & 15, quad = lane >> 4;
  f32x4 acc[2][2];
  const f32x4 z = {0.f, 0.f, 0.f, 0.f};
  acc[0][0] = z; acc[0][1] = z; acc[1][0] = z; acc[1][1] = z;

  const int srow = wave * 16 + (lane >> 2), scol = (lane & 3) * 8;
  const unsigned short* Ag = A + (long)(bm + srow) * 1024 + scol;
  const unsigned short* Bg = B + (long)(bn + srow) * 1024 + scol;

#define G2_STAGE(nb, ko)                                           \
  do {                                                             \
    gl_lds16(Ag + (ko),      As + (nb) * 4096 + wave * 512);       \
    gl_lds16(Ag + (ko) + 32, As + (nb) * 4096 + 2048 + wave * 512);\
    gl_lds16(Bg + (ko),      Bs + (nb) * 4096 + wave * 512);       \
    gl_lds16(Bg + (ko) + 32, Bs + (nb) * 4096 + 2048 + wave * 512);\
  } while (0)

#define G2_COMPUTE(b)                                                   \
  do {                                                                  \
    _Pragma("unroll")                                                   \
    for (int half = 0; half < 2; half++){                               \
      const unsigned short* Ah = As + (b) * 4096 + half * 2048;         \
      const unsigned short* Bh = Bs + (b) * 4096 + half * 2048;         \
      short8 a0f = *(const short8*)&Ah[(wm + ml) * 32 + quad * 8];      \
      short8 a1f = *(const short8*)&Ah[(wm + 16 + ml) * 32 + quad * 8]; \
      short8 b0f = *(const short8*)&Bh[(wn + ml) * 32 + quad * 8];      \
      short8 b1f = *(const short8*)&Bh[(wn + 16 + ml) * 32 + quad * 8]; \
      acc[0][0] = MFMA32(a0f, b0f, acc[0][0]);                          \
      acc[0][1] = MFMA32(a0f, b1f, acc[0][1]);                          \
      acc[1][0] = MFMA32(a1f, b0f, acc[1][0]);                          \
      acc[1][1] = MFMA32(a1f, b1f, acc[1][1]);                          \
    }                                                                   \
  } while (0)

  G2_STAGE(0, 0);
  __syncthreads();
  for (int kk = 0; kk < 1024; kk += 128){
    G2_STAGE(1, kk + 64);
    G2_COMPUTE(0);
    __syncthreads();
    if (kk + 128 < 1024) G2_STAGE(0, kk + 128);
    G2_COMPUTE(1);
    __syncthreads();
  }
#undef G2_STAGE
#undef G2_COMPUTE

#pragma unroll
  for (int i = 0; i < 2; i++)
#pragma unroll
    for (int j = 0; j < 2; j++)
#pragma unroll
      for (int r = 0; r < 4; r++)
        C[(long)(bm + wm + i * 16 + quad * 4 + r) * 1024 + bn + wn + j * 16 + ml] = acc[i][j][r];
}

extern "C" void kernel_launch(void* const* d_in, const int* in_sizes, int n_in,
                              void* d_out, int out_size, void* d_ws, size_t ws_size,
                              hipStream_t stream){
  const float* x    = (const float*)d_in[0];
  const float* qw   = (const float*)d_in[1];
  const float* kw   = (const float*)d_in[2];
  const float* vw   = (const float*)d_in[3];
  const float* ow   = (const float*)d_in[4];
  const float* temp = (const float*)d_in[5];
  const float* curv = (const float*)d_in[6];
  float* out = (float*)d_out;

  char* ws = (char*)d_ws;
  size_t off = 0;
  auto alloc = [&](size_t bytes) -> char* {
    char* p = ws + off;
    off += (bytes + 255) & ~(size_t)255;
    return p;
  };
  unsigned short* xb   = (unsigned short*)alloc((size_t)TT * DM * 2);        // 4 MB
  unsigned short* wqkv = (unsigned short*)alloc((size_t)1536 * DM * 2);      // 3 MB
  unsigned short* owb  = (unsigned short*)alloc((size_t)DM * DM * 2);        // 2 MB
  unsigned short* qb   = (unsigned short*)alloc((size_t)NH * TT * HD * 2);   // 4 MB
  unsigned short* kb   = (unsigned short*)alloc((size_t)NKV * TT * HD * 2);  // 1 MB
  unsigned short* vt   = (unsigned short*)alloc((size_t)NKV * TT * HD * 2);  // 1 MB
  float*          q0   = (float*)alloc((size_t)NH * TT * 4);
  float*          k0   = (float*)alloc((size_t)NKV * TT * 4);
  unsigned short* attn = (unsigned short*)alloc((size_t)TT * DM * 2);        // 4 MB
  float*          bpart= (float*)alloc((size_t)768 * 4);

  convertw_kernel<<<4608, 256, 0, stream>>>(x, qw, kw, vw, ow, xb, wqkv, owb);
  gemm1_fused<<<dim3(24, 32), 256, 0, stream>>>(xb, wqkv, qb, kb, vt, q0, k0, bpart, curv);
  attn_kernel<<<1024, 256, 0, stream>>>(qb, kb, vt, q0, k0, temp, curv, attn,
                                        bpart, out + (size_t)TT * DM);
  gemm2_kernel<<<dim3(16, 32), 256, 0, stream>>>(attn, owb, out);
}

// Round 2
// 143.418 us; speedup vs baseline: 1.0290x; 1.0290x over previous
//
#include <hip/hip_runtime.h>
#include <hip/hip_bf16.h>

typedef __attribute__((ext_vector_type(8))) short short8;
typedef __attribute__((ext_vector_type(4))) short bf16x4;
typedef __attribute__((ext_vector_type(4))) float f32x4;

#define TT 2048   // sequence length
#define DM 1024   // model dim
#define NH 16     // query heads
#define NKV 4     // kv heads
#define HD 64     // head dim

#define MFMA32(a,b,c) __builtin_amdgcn_mfma_f32_16x16x32_bf16(a,b,c,0,0,0)
#define MFMA16(a,b,c) __builtin_amdgcn_mfma_f32_16x16x16bf16_1k(a,b,c,0,0,0)

__device__ __forceinline__ unsigned short f2bf(float x){
  unsigned int u = __float_as_uint(x);
  u += 0x7fffu + ((u >> 16) & 1u);   // RNE
  return (unsigned short)(u >> 16);
}
// packed 2xfp32 -> 2xbf16 (v_cvt_pk_bf16_f32 on gfx950)
__device__ __forceinline__ unsigned int pkbf2(float x, float y){
  union { __hip_bfloat162 h; unsigned int u; } t;
  t.h = __float22bfloat162_rn(make_float2(x, y));
  return t.u;
}
// async global->LDS, 16B/lane; lds dest = wave-uniform base + lane*16
__device__ __forceinline__ void gl_lds16(const unsigned short* g, unsigned short* l){
  __builtin_amdgcn_global_load_lds(
      (__attribute__((address_space(1))) void*)g,
      (__attribute__((address_space(3))) void*)l, 16, 0, 0);
}

// ---------------- 1. x + weights fp32 -> bf16 ----------------
__global__ __launch_bounds__(256) void convertw_kernel(
    const float* __restrict__ x,
    const float* __restrict__ qw, const float* __restrict__ kw,
    const float* __restrict__ vw, const float* __restrict__ ow,
    unsigned short* __restrict__ xb,
    unsigned short* __restrict__ wqkv, unsigned short* __restrict__ owb){
  long v = (long)blockIdx.x * 256 + threadIdx.x;
  const float* src; unsigned short* dst; long base;
  if      (v < 524288) { src = x;  dst = xb;             base = v; }
  else if (v < 786432) { src = qw; dst = wqkv;           base = v - 524288; }
  else if (v < 851968) { src = kw; dst = wqkv + 1048576; base = v - 786432; }
  else if (v < 917504) { src = vw; dst = wqkv + 1310720; base = v - 851968; }
  else                 { src = ow; dst = owb;            base = v - 917504; }
  f32x4 d = *(const f32x4*)(src + base * 4);
  uint2 pk = { pkbf2(d[0], d[1]), pkbf2(d[2], d[3]) };
  *(uint2*)(dst + base * 4) = pk;
}

// ---------------- 2. QKV GEMM, 128t x 64f blocks, in-register fused epilogue ----
// grid dim3(24, 16): x = head (0..15 q | 16..19 k | 20..23 v), y = 128-row t-tile.
// Wave w owns rows [bm + w*32, +32) x ALL 64 features of the head:
//   acc[i][j]: t = bm + w*32 + i*16 + quad*4 + r, feature d = j*16 + ml.
// -> RMSNorm reduce = 3 in-lane adds + 4 independent shfl_xor (ml group);
//    RoPE pair (d, d+32) = (j, j+2) in-register; V-transpose in-register.
// K-loop: BK=64 single-buffered (m97 pattern), 12 ds_read_b128 / 16 MFMA / 2 barriers.
__global__ __launch_bounds__(256) void gemm1_fused(
    const unsigned short* __restrict__ xb, const unsigned short* __restrict__ wqkv,
    unsigned short* __restrict__ qb, unsigned short* __restrict__ kb,
    unsigned short* __restrict__ vt,
    float* __restrict__ q0, float* __restrict__ k0,
    float* __restrict__ bpart, const float* __restrict__ curv){
  __shared__ __align__(16) unsigned short As[2 * 128 * 32];  // 16 KB (two K-halves)
  __shared__ __align__(16) unsigned short Bs[2 * 64 * 32];   //  8 KB
  __shared__ float bsum;
  const int tid = threadIdx.x, lane = tid & 63, wave = tid >> 6;
  const int hIdx = blockIdx.x;
  const int bm = blockIdx.y * 128, bn = hIdx * 64;
  const int ml = lane & 15, quad = lane >> 4;
  if (tid == 0) bsum = 0.f;
  f32x4 acc[2][4];
  const f32x4 z = {0.f, 0.f, 0.f, 0.f};
#pragma unroll
  for (int i = 0; i < 2; i++)
#pragma unroll
    for (int j = 0; j < 4; j++) acc[i][j] = z;

  // staging: 256 threads, thread -> row tid/4, col (tid&3)*8 shorts (16B).
  // Each gl_lds16 call covers 64 rows; wave w's 64 lanes land at base + w*1KB.
  const int srow = tid >> 2, scol = (tid & 3) * 8;
  const unsigned short* Ag0 = xb   + (long)(bm + srow) * 1024 + scol;        // rows 0..63
  const unsigned short* Ag1 = Ag0 + 64 * 1024;                               // rows 64..127
  const unsigned short* Bg  = wqkv + (long)(bn + srow) * 1024 + scol;
  unsigned short* Asw = As + wave * 512;
  unsigned short* Bsw = Bs + wave * 512;

  for (int kk = 0; kk < 1024; kk += 64){
    __syncthreads();                       // LDS free
    gl_lds16(Ag0 + kk,      Asw);          // half0 rows 0..63
    gl_lds16(Ag1 + kk,      Asw + 2048);   // half0 rows 64..127
    gl_lds16(Bg  + kk,      Bsw);          // half0
    gl_lds16(Ag0 + kk + 32, Asw + 4096);   // half1
    gl_lds16(Ag1 + kk + 32, Asw + 4096 + 2048);
    gl_lds16(Bg  + kk + 32, Bs + 2048 + wave * 512);
    __syncthreads();                       // vmcnt drained by barrier
#pragma unroll
    for (int half = 0; half < 2; half++){
      const unsigned short* Ah = As + half * 4096;
      const unsigned short* Bh = Bs + half * 2048;
      short8 a0 = *(const short8*)&Ah[(wave * 32 + ml) * 32 + quad * 8];
      short8 a1 = *(const short8*)&Ah[(wave * 32 + 16 + ml) * 32 + quad * 8];
      short8 b0 = *(const short8*)&Bh[(ml) * 32 + quad * 8];
      short8 b1 = *(const short8*)&Bh[(16 + ml) * 32 + quad * 8];
      short8 b2 = *(const short8*)&Bh[(32 + ml) * 32 + quad * 8];
      short8 b3 = *(const short8*)&Bh[(48 + ml) * 32 + quad * 8];
      acc[0][0] = MFMA32(a0, b0, acc[0][0]);
      acc[0][1] = MFMA32(a0, b1, acc[0][1]);
      acc[0][2] = MFMA32(a0, b2, acc[0][2]);
      acc[0][3] = MFMA32(a0, b3, acc[0][3]);
      acc[1][0] = MFMA32(a1, b0, acc[1][0]);
      acc[1][1] = MFMA32(a1, b1, acc[1][1]);
      acc[1][2] = MFMA32(a1, b2, acc[1][2]);
      acc[1][3] = MFMA32(a1, b3, acc[1][3]);
    }
  }

  if (hIdx < 20){
    // RMSNorm + RoPE + q0/k0 (+ spatial partial for q), fully in-register.
    const bool isq = hIdx < 16;
    const int h = isq ? hIdx : hIdx - 16;
    const float c = curv[0];
    unsigned short* ob = isq ? qb : kb;
    float* o0p = isq ? q0 : k0;
    // inv_freq for this lane's two freq indices: fi = ml and 16+ml
    const float if0 = __builtin_amdgcn_exp2f((float)ml        * (-13.287712379549449f / 32.f));
    const float if1 = __builtin_amdgcn_exp2f((float)(16 + ml) * (-13.287712379549449f / 32.f));
    float bl = 0.f;
#pragma unroll
    for (int i = 0; i < 2; i++){
#pragma unroll
      for (int r = 0; r < 4; r++){
        const int t = bm + wave * 32 + i * 16 + quad * 4 + r;
        float v0 = acc[i][0][r], v1 = acc[i][1][r], v2 = acc[i][2][r], v3 = acc[i][3][r];
        float ss = v0 * v0 + v1 * v1 + v2 * v2 + v3 * v3;
        ss += __shfl_xor(ss, 1); ss += __shfl_xor(ss, 2);
        ss += __shfl_xor(ss, 4); ss += __shfl_xor(ss, 8);
        float scale = __builtin_amdgcn_rsqf(ss * (1.f / 64.f) + 1e-6f);
        float x0 = v0 * scale, x1 = v1 * scale, x2 = v2 * scale, x3 = v3 * scale;
        float sn0, cs0, sn1, cs1;
        __sincosf((float)t * if0, &sn0, &cs0);
        __sincosf((float)t * if1, &sn1, &cs1);
        unsigned short* op = ob + ((long)h * TT + t) * 64;
        op[ml]      = f2bf( x0 * cs0 + x2 * sn0);
        op[16 + ml] = f2bf( x1 * cs1 + x3 * sn1);
        op[32 + ml] = f2bf( x2 * cs0 - x0 * sn0);
        op[48 + ml] = f2bf( x3 * cs1 - x1 * sn1);
        if (ml == 0){
          float sq = ss * scale * scale;    // |normed|^2, rope preserves norm
          o0p[h * TT + t] = __builtin_amdgcn_sqrtf(1.f / c + sq);
          if (isq) bl += __builtin_amdgcn_sqrtf(sq);
        }
      }
    }
    if (isq && ml == 0) atomicAdd(&bsum, bl);
  } else {
    // V: bf16 + PV-fragment order vt[hk][tile][d][key16], in-register transpose:
    // key16 = quad*4 + r (contiguous per lane) -> one 8B store per (i,j)
    const int hk = hIdx - 20;
#pragma unroll
    for (int i = 0; i < 2; i++){
      const int tile = (bm >> 4) + wave * 2 + i;
#pragma unroll
      for (int j = 0; j < 4; j++){
        uint2 w2 = { pkbf2(acc[i][j][0], acc[i][j][1]), pkbf2(acc[i][j][2], acc[i][j][3]) };
        unsigned short* dst = vt + ((long)(hk * 128 + tile) * 64 + j * 16 + ml) * 16 + quad * 4;
        *(uint2*)dst = w2;
      }
    }
  }
  __syncthreads();
  if (tid == 0) bpart[blockIdx.y * 24 + hIdx] = bsum;
}

// ---------------- 3. head-pair-fused hyperbolic causal attention -------
__global__ __launch_bounds__(256, 3) void attn_kernel(
    const unsigned short* __restrict__ qb_, const unsigned short* __restrict__ kb_,
    const unsigned short* __restrict__ vt_,
    const float* __restrict__ q0_, const float* __restrict__ k0_,
    const float* __restrict__ temp, const float* __restrict__ curv,
    unsigned short* __restrict__ attn_out,
    const float* __restrict__ bpart, float* __restrict__ out_scalar){
  __shared__ float lds[8 * 1104];    // regions: wave (head0), 4+wave (head1)
  const int tid = threadIdx.x, lane = tid & 63, wave = tid >> 6;
  const int qt  = 127 - (blockIdx.x >> 3);     // longest-first
  const int sub = blockIdx.x & 7;
  const int kvh = sub >> 1, hp = sub & 1;
  const int h0 = kvh * 4 + hp * 2, h1 = h0 + 1;
  const int i0 = qt * 16;
  const int ml = lane & 15, quad = lane >> 4;
  const float c = curv[0];
  const float rsc = __builtin_amdgcn_rsqf(c);
  const float fac0 = -rsc / temp[h0];
  const float fac1 = -rsc / temp[h1];
  const f32x4 z = {0.f, 0.f, 0.f, 0.f};
  const unsigned short* kh = kb_ + (long)kvh * TT * 64;
  const unsigned short* vh = vt_ + (long)kvh * 128 * 1024;   // [tile][d][key16]
  const float* k0h = k0_ + kvh * TT;

  short8 qa0 = *(const short8*)&qb_[((long)h0 * TT + i0 + ml) * 64 + quad * 8];
  short8 qa1 = *(const short8*)&qb_[((long)h0 * TT + i0 + ml) * 64 + 32 + quad * 8];
  short8 qb0 = *(const short8*)&qb_[((long)h1 * TT + i0 + ml) * 64 + quad * 8];
  short8 qb1 = *(const short8*)&qb_[((long)h1 * TT + i0 + ml) * 64 + 32 + quad * 8];
  const float q0c0 = c * q0_[h0 * TT + i0 + ml];   // per-lane: q = i0+ml
  const float q0c1 = c * q0_[h1 * TT + i0 + ml];
  const int rowq = i0 + ml;

  f32x4 o0[4], o1[4];
#pragma unroll
  for (int dt = 0; dt < 4; dt++){ o0[dt] = z; o1[dt] = z; }
  float l0 = 0.f, l1 = 0.f;

  const int nt = (i0 + 47) >> 5;   // 32-key tiles

#pragma unroll 1
  for (int t = wave; t < nt; t += 4){
    const int j0 = t << 5;
    const unsigned short* kp = kh + (long)j0 * 64;
    short8 ka0 = *(const short8*)(kp + ml * 64 + quad * 8);
    short8 ka1 = *(const short8*)(kp + ml * 64 + 32 + quad * 8);
    short8 kc0 = *(const short8*)(kp + (16 + ml) * 64 + quad * 8);
    short8 kc1 = *(const short8*)(kp + (16 + ml) * 64 + 32 + quad * 8);
    f32x4 k0a = *(const f32x4*)(k0h + j0 + quad * 4);
    f32x4 k0b = *(const f32x4*)(k0h + j0 + 16 + quad * 4);
    const unsigned short* vpa = vh + (long)(j0 >> 4) * 1024;
    bf16x4 vfa0 = *(const bf16x4*)(vpa + ( 0 + ml) * 16 + quad * 4);
    bf16x4 vfa1 = *(const bf16x4*)(vpa + (16 + ml) * 16 + quad * 4);
    bf16x4 vfa2 = *(const bf16x4*)(vpa + (32 + ml) * 16 + quad * 4);
    bf16x4 vfa3 = *(const bf16x4*)(vpa + (48 + ml) * 16 + quad * 4);
    bf16x4 vfb0 = *(const bf16x4*)(vpa + 1024 + ( 0 + ml) * 16 + quad * 4);
    bf16x4 vfb1 = *(const bf16x4*)(vpa + 1024 + (16 + ml) * 16 + quad * 4);
    bf16x4 vfb2 = *(const bf16x4*)(vpa + 1024 + (32 + ml) * 16 + quad * 4);
    bf16x4 vfb3 = *(const bf16x4*)(vpa + 1024 + (48 + ml) * 16 + quad * 4);

    const int keyb = j0 + quad * 4;
    const bool nm = (j0 + 31 > i0);
    // ---- head 0 ----
    {
      f32x4 s0 = z, s1 = z;
      s0 = MFMA32(ka0, qa0, s0);
      s0 = MFMA32(ka1, qa1, s0);
      s1 = MFMA32(kc0, qa0, s1);
      s1 = MFMA32(kc1, qa1, s1);
      float p0[4], p1[4];
#pragma unroll
      for (int r = 0; r < 4; r++){
        float argA = fmaxf(__builtin_fmaf(-c, s0[r], q0c0 * k0a[r]), 1.00001f);
        float wA   = argA + __builtin_amdgcn_sqrtf(__builtin_fmaf(argA, argA, -1.f));
        float pA   = __builtin_amdgcn_exp2f(fac0 * __builtin_amdgcn_logf(wA));
        float argB = fmaxf(__builtin_fmaf(-c, s1[r], q0c0 * k0b[r]), 1.00001f);
        float wB   = argB + __builtin_amdgcn_sqrtf(__builtin_fmaf(argB, argB, -1.f));
        float pB   = __builtin_amdgcn_exp2f(fac0 * __builtin_amdgcn_logf(wB));
        if (nm){
          if (keyb + r > rowq)      pA = 0.f;
          if (keyb + 16 + r > rowq) pB = 0.f;
        }
        p0[r] = pA; p1[r] = pB;
        l0 += pA + pB;
      }
      uint2 pua = { pkbf2(p0[0], p0[1]), pkbf2(p0[2], p0[3]) };
      uint2 pub = { pkbf2(p1[0], p1[1]), pkbf2(p1[2], p1[3]) };
      bf16x4 pfa = *(bf16x4*)&pua;
      bf16x4 pfb = *(bf16x4*)&pub;
      o0[0] = MFMA16(vfa0, pfa, o0[0]);
      o0[1] = MFMA16(vfa1, pfa, o0[1]);
      o0[2] = MFMA16(vfa2, pfa, o0[2]);
      o0[3] = MFMA16(vfa3, pfa, o0[3]);
      o0[0] = MFMA16(vfb0, pfb, o0[0]);
      o0[1] = MFMA16(vfb1, pfb, o0[1]);
      o0[2] = MFMA16(vfb2, pfb, o0[2]);
      o0[3] = MFMA16(vfb3, pfb, o0[3]);
    }
    // ---- head 1 (same K/V tile) ----
    {
      f32x4 s0 = z, s1 = z;
      s0 = MFMA32(ka0, qb0, s0);
      s0 = MFMA32(ka1, qb1, s0);
      s1 = MFMA32(kc0, qb0, s1);
      s1 = MFMA32(kc1, qb1, s1);
      float p0[4], p1[4];
#pragma unroll
      for (int r = 0; r < 4; r++){
        float argA = fmaxf(__builtin_fmaf(-c, s0[r], q0c1 * k0a[r]), 1.00001f);
        float wA   = argA + __builtin_amdgcn_sqrtf(__builtin_fmaf(argA, argA, -1.f));
        float pA   = __builtin_amdgcn_exp2f(fac1 * __builtin_amdgcn_logf(wA));
        float argB = fmaxf(__builtin_fmaf(-c, s1[r], q0c1 * k0b[r]), 1.00001f);
        float wB   = argB + __builtin_amdgcn_sqrtf(__builtin_fmaf(argB, argB, -1.f));
        float pB   = __builtin_amdgcn_exp2f(fac1 * __builtin_amdgcn_logf(wB));
        if (nm){
          if (keyb + r > rowq)      pA = 0.f;
          if (keyb + 16 + r > rowq) pB = 0.f;
        }
        p0[r] = pA; p1[r] = pB;
        l1 += pA + pB;
      }
      uint2 pua = { pkbf2(p0[0], p0[1]), pkbf2(p0[2], p0[3]) };
      uint2 pub = { pkbf2(p1[0], p1[1]), pkbf2(p1[2], p1[3]) };
      bf16x4 pfa = *(bf16x4*)&pua;
      bf16x4 pfb = *(bf16x4*)&pub;
      o1[0] = MFMA16(vfa0, pfa, o1[0]);
      o1[1] = MFMA16(vfa1, pfa, o1[1]);
      o1[2] = MFMA16(vfa2, pfa, o1[2]);
      o1[3] = MFMA16(vfa3, pfa, o1[3]);
      o1[0] = MFMA16(vfb0, pfb, o1[0]);
      o1[1] = MFMA16(vfb1, pfb, o1[1]);
      o1[2] = MFMA16(vfb2, pfb, o1[2]);
      o1[3] = MFMA16(vfb3, pfb, o1[3]);
    }
  }
  // l across quads (keys split over quads/regs; q=ml fixed)
  l0 += __shfl_xor(l0, 16); l0 += __shfl_xor(l0, 32);
  l1 += __shfl_xor(l1, 16); l1 += __shfl_xor(l1, 32);
  // publish wave partials: O^T reg r -> d = dt*16+quad*4+r at q=ml
  {
    float* w0 = lds + wave * 1104;
    float* w1 = lds + (4 + wave) * 1104;
#pragma unroll
    for (int dt = 0; dt < 4; dt++){
      *(f32x4*)&w0[ml * 68 + dt * 16 + quad * 4] = o0[dt];
      *(f32x4*)&w1[ml * 68 + dt * 16 + quad * 4] = o1[dt];
    }
    if (quad == 0){ w0[1088 + ml] = l0; w1[1088 + ml] = l1; }
  }
  __syncthreads();
  // merge 4 waves per head: thread -> (row = tid>>4, 4 d's)
  {
    const int row = tid >> 4, c0 = (tid & 15) * 4;
#pragma unroll 1
    for (int hb = 0; hb < 2; hb++){
      const float* base = lds + hb * 4 * 1104;
      float L = 0.f; f32x4 s = z;
#pragma unroll
      for (int w = 0; w < 4; w++){
        const float* rg = base + w * 1104;
        L += rg[1088 + row];
        f32x4 t2 = *(const f32x4*)&rg[row * 68 + c0];
        s[0] += t2[0]; s[1] += t2[1]; s[2] += t2[2]; s[3] += t2[3];
      }
      float invL = __builtin_amdgcn_rcpf(L);
      const int h = hb ? h1 : h0;
      uint2 o = { pkbf2(s[0] * invL, s[1] * invL), pkbf2(s[2] * invL, s[3] * invL) };
      *(uint2*)&attn_out[(long)(i0 + row) * 1024 + h * 64 + c0] = o;
    }
  }
  // fused spatial_norm finalize (bpart now 16*24 = 384 entries)
  if (blockIdx.x == 0 && tid < 64){
    float s = 0.f;
    for (int i = lane; i < 384; i += 64) s += bpart[i];
#pragma unroll
    for (int off = 1; off < 64; off <<= 1) s += __shfl_xor(s, off);
    if (lane == 0) out_scalar[0] = s * (1.f / 32768.f);
  }
}

// ---------------- 4. O-proj GEMM (2-phase double-buffered staging): out = attn x owb^T
__global__ __launch_bounds__(256) void gemm2_kernel(
    const unsigned short* __restrict__ A, const unsigned short* __restrict__ B,
    float* __restrict__ C){
  __shared__ __align__(16) unsigned short As[2 * 4096];  // [buf][half][64][32] 16 KB
  __shared__ __align__(16) unsigned short Bs[2 * 4096];
  const int tid = threadIdx.x, lane = tid & 63, wave = tid >> 6;
  const int bm = blockIdx.y * 64, bn = blockIdx.x * 64;
  const int wm = (wave >> 1) * 32, wn = (wave & 1) * 32;
  const int ml = lane & 15, quad = lane >> 4;
  f32x4 acc[2][2];
  const f32x4 z = {0.f, 0.f, 0.f, 0.f};
  acc[0][0] = z; acc[0][1] = z; acc[1][0] = z; acc[1][1] = z;

  const int srow = wave * 16 + (lane >> 2), scol = (lane & 3) * 8;
  const unsigned short* Ag = A + (long)(bm + srow) * 1024 + scol;
  const unsigned short* Bg = B + (long)(bn + srow) * 1024 + scol;

#define G2_STAGE(nb, ko)                                           \
  do {                                                             \
    gl_lds16(Ag + (ko),      As + (nb) * 4096 + wave * 512);       \
    gl_lds16(Ag + (ko) + 32, As + (nb) * 4096 + 2048 + wave * 512);\
    gl_lds16(Bg + (ko),      Bs + (nb) * 4096 + wave * 512);       \
    gl_lds16(Bg + (ko) + 32, Bs + (nb) * 4096 + 2048 + wave * 512);\
  } while (0)

#define G2_COMPUTE(b)                                                   \
  do {                                                                  \
    _Pragma("unroll")                                                   \
    for (int half = 0; half < 2; half++){                               \
      const unsigned short* Ah = As + (b) * 4096 + half * 2048;         \
      const unsigned short* Bh = Bs + (b) * 4096 + half * 2048;         \
      short8 a0f = *(const short8*)&Ah[(wm + ml) * 32 + quad * 8];      \
      short8 a1f = *(const short8*)&Ah[(wm + 16 + ml) * 32 + quad * 8]; \
      short8 b0f = *(const short8*)&Bh[(wn + ml) * 32 + quad * 8];      \
      short8 b1f = *(const short8*)&Bh[(wn + 16 + ml) * 32 + quad * 8]; \
      acc[0][0] = MFMA32(a0f, b0f, acc[0][0]);                          \
      acc[0][1] = MFMA32(a0f, b1f, acc[0][1]);                          \
      acc[1][0] = MFMA32(a1f, b0f, acc[1][0]);                          \
      acc[1][1] = MFMA32(a1f, b1f, acc[1][1]);                          \
    }                                                                   \
  } while (0)

  G2_STAGE(0, 0);
  __syncthreads();
  for (int kk = 0; kk < 1024; kk += 128){
    G2_STAGE(1, kk + 64);
    G2_COMPUTE(0);
    __syncthreads();
    if (kk + 128 < 1024) G2_STAGE(0, kk + 128);
    G2_COMPUTE(1);
    __syncthreads();
  }
#undef G2_STAGE
#undef G2_COMPUTE

#pragma unroll
  for (int i = 0; i < 2; i++)
#pragma unroll
    for (int j = 0; j < 2; j++)
#pragma unroll
      for (int r = 0; r < 4; r++)
        C[(long)(bm + wm + i * 16 + quad * 4 + r) * 1024 + bn + wn + j * 16 + ml] = acc[i][j][r];
}

extern "C" void kernel_launch(void* const* d_in, const int* in_sizes, int n_in,
                              void* d_out, int out_size, void* d_ws, size_t ws_size,
                              hipStream_t stream){
  const float* x    = (const float*)d_in[0];
  const float* qw   = (const float*)d_in[1];
  const float* kw   = (const float*)d_in[2];
  const float* vw   = (const float*)d_in[3];
  const float* ow   = (const float*)d_in[4];
  const float* temp = (const float*)d_in[5];
  const float* curv = (const float*)d_in[6];
  float* out = (float*)d_out;

  char* ws = (char*)d_ws;
  size_t off = 0;
  auto alloc = [&](size_t bytes) -> char* {
    char* p = ws + off;
    off += (bytes + 255) & ~(size_t)255;
    return p;
  };
  unsigned short* xb   = (unsigned short*)alloc((size_t)TT * DM * 2);        // 4 MB
  unsigned short* wqkv = (unsigned short*)alloc((size_t)1536 * DM * 2);      // 3 MB
  unsigned short* owb  = (unsigned short*)alloc((size_t)DM * DM * 2);        // 2 MB
  unsigned short* qb   = (unsigned short*)alloc((size_t)NH * TT * HD * 2);   // 4 MB
  unsigned short* kb   = (unsigned short*)alloc((size_t)NKV * TT * HD * 2);  // 1 MB
  unsigned short* vt   = (unsigned short*)alloc((size_t)NKV * TT * HD * 2);  // 1 MB
  float*          q0   = (float*)alloc((size_t)NH * TT * 4);
  float*          k0   = (float*)alloc((size_t)NKV * TT * 4);
  unsigned short* attn = (unsigned short*)alloc((size_t)TT * DM * 2);        // 4 MB
  float*          bpart= (float*)alloc((size_t)768 * 4);

  convertw_kernel<<<4608, 256, 0, stream>>>(x, qw, kw, vw, ow, xb, wqkv, owb);
  gemm1_fused<<<dim3(24, 16), 256, 0, stream>>>(xb, wqkv, qb, kb, vt, q0, k0, bpart, curv);
  attn_kernel<<<1024, 256, 0, stream>>>(qb, kb, vt, q0, k0, temp, curv, attn,
                                        bpart, out + (size_t)TT * DM);
  gemm2_kernel<<<dim3(16, 32), 256, 0, stream>>>(attn, owb, out);
}

// Round 3
// 140.145 us; speedup vs baseline: 1.0531x; 1.0233x over previous
//
#include <hip/hip_runtime.h>
#include <hip/hip_bf16.h>

typedef __attribute__((ext_vector_type(8))) short short8;
typedef __attribute__((ext_vector_type(4))) short bf16x4;
typedef __attribute__((ext_vector_type(4))) float f32x4;

#define TT 2048   // sequence length
#define DM 1024   // model dim
#define NH 16     // query heads
#define NKV 4     // kv heads
#define HD 64     // head dim

#define MFMA32(a,b,c) __builtin_amdgcn_mfma_f32_16x16x32_bf16(a,b,c,0,0,0)
#define MFMA16(a,b,c) __builtin_amdgcn_mfma_f32_16x16x16bf16_1k(a,b,c,0,0,0)

__device__ __forceinline__ unsigned short f2bf(float x){
  unsigned int u = __float_as_uint(x);
  u += 0x7fffu + ((u >> 16) & 1u);   // RNE
  return (unsigned short)(u >> 16);
}
// packed 2xfp32 -> 2xbf16 (v_cvt_pk_bf16_f32 on gfx950)
__device__ __forceinline__ unsigned int pkbf2(float x, float y){
  union { __hip_bfloat162 h; unsigned int u; } t;
  t.h = __float22bfloat162_rn(make_float2(x, y));
  return t.u;
}
// async global->LDS, 16B/lane; lds dest = wave-uniform base + lane*16
__device__ __forceinline__ void gl_lds16(const unsigned short* g, unsigned short* l){
  __builtin_amdgcn_global_load_lds(
      (__attribute__((address_space(1))) void*)g,
      (__attribute__((address_space(3))) void*)l, 16, 0, 0);
}

// ---------------- 1. x + weights fp32 -> bf16 ----------------
__global__ __launch_bounds__(256) void convertw_kernel(
    const float* __restrict__ x,
    const float* __restrict__ qw, const float* __restrict__ kw,
    const float* __restrict__ vw, const float* __restrict__ ow,
    unsigned short* __restrict__ xb,
    unsigned short* __restrict__ wqkv, unsigned short* __restrict__ owb){
  long v = (long)blockIdx.x * 256 + threadIdx.x;
  const float* src; unsigned short* dst; long base;
  if      (v < 524288) { src = x;  dst = xb;             base = v; }
  else if (v < 786432) { src = qw; dst = wqkv;           base = v - 524288; }
  else if (v < 851968) { src = kw; dst = wqkv + 1048576; base = v - 786432; }
  else if (v < 917504) { src = vw; dst = wqkv + 1310720; base = v - 851968; }
  else                 { src = ow; dst = owb;            base = v - 917504; }
  f32x4 d = *(const f32x4*)(src + base * 4);
  uint2 pk = { pkbf2(d[0], d[1]), pkbf2(d[2], d[3]) };
  *(uint2*)(dst + base * 4) = pk;
}

// ---------------- 2. QKV GEMM, 128t x 64f blocks, BK=128, in-register fused epilogue
// grid dim3(24, 16): x = head (0..15 q | 16..19 k | 20..23 v), y = 128-row t-tile.
// Wave w owns rows [bm + w*32, +32) x ALL 64 features of the head:
//   acc[i][j]: t = bm + w*32 + i*16 + quad*4 + r, feature d = j*16 + ml.
// K-loop: BK=128 = four [.][32]-short halves staged per barrier pair:
//   12 gl_lds16 in flight / 32 MFMA / 2 barriers per K-step.
__global__ __launch_bounds__(256) void gemm1_fused(
    const unsigned short* __restrict__ xb, const unsigned short* __restrict__ wqkv,
    unsigned short* __restrict__ qb, unsigned short* __restrict__ kb,
    unsigned short* __restrict__ vt,
    float* __restrict__ q0, float* __restrict__ k0,
    float* __restrict__ bpart, const float* __restrict__ curv){
  __shared__ __align__(16) unsigned short As[4 * 128 * 32];  // 32 KB (4 K-halves)
  __shared__ __align__(16) unsigned short Bs[4 * 64 * 32];   // 16 KB
  __shared__ float bsum;
  const int tid = threadIdx.x, lane = tid & 63, wave = tid >> 6;
  const int hIdx = blockIdx.x;
  const int bm = blockIdx.y * 128, bn = hIdx * 64;
  const int ml = lane & 15, quad = lane >> 4;
  if (tid == 0) bsum = 0.f;
  f32x4 acc[2][4];
  const f32x4 z = {0.f, 0.f, 0.f, 0.f};
#pragma unroll
  for (int i = 0; i < 2; i++)
#pragma unroll
    for (int j = 0; j < 4; j++) acc[i][j] = z;

  // staging: 256 threads, thread -> row tid/4, col (tid&3)*8 shorts (16B).
  // Each gl_lds16 call covers 64 rows; wave w's 64 lanes land at base + w*1KB.
  const int srow = tid >> 2, scol = (tid & 3) * 8;
  const unsigned short* Ag0 = xb   + (long)(bm + srow) * 1024 + scol;        // rows 0..63
  const unsigned short* Ag1 = Ag0 + 64 * 1024;                               // rows 64..127
  const unsigned short* Bg  = wqkv + (long)(bn + srow) * 1024 + scol;

  for (int kk = 0; kk < 1024; kk += 128){
    __syncthreads();                       // LDS free
#pragma unroll
    for (int half = 0; half < 4; half++){
      gl_lds16(Ag0 + kk + half * 32, As + half * 4096 + wave * 512);
      gl_lds16(Ag1 + kk + half * 32, As + half * 4096 + 2048 + wave * 512);
      gl_lds16(Bg  + kk + half * 32, Bs + half * 2048 + wave * 512);
    }
    __syncthreads();                       // vmcnt drained by barrier
#pragma unroll
    for (int half = 0; half < 4; half++){
      const unsigned short* Ah = As + half * 4096;
      const unsigned short* Bh = Bs + half * 2048;
      short8 a0 = *(const short8*)&Ah[(wave * 32 + ml) * 32 + quad * 8];
      short8 a1 = *(const short8*)&Ah[(wave * 32 + 16 + ml) * 32 + quad * 8];
      short8 b0 = *(const short8*)&Bh[(ml) * 32 + quad * 8];
      short8 b1 = *(const short8*)&Bh[(16 + ml) * 32 + quad * 8];
      short8 b2 = *(const short8*)&Bh[(32 + ml) * 32 + quad * 8];
      short8 b3 = *(const short8*)&Bh[(48 + ml) * 32 + quad * 8];
      acc[0][0] = MFMA32(a0, b0, acc[0][0]);
      acc[0][1] = MFMA32(a0, b1, acc[0][1]);
      acc[0][2] = MFMA32(a0, b2, acc[0][2]);
      acc[0][3] = MFMA32(a0, b3, acc[0][3]);
      acc[1][0] = MFMA32(a1, b0, acc[1][0]);
      acc[1][1] = MFMA32(a1, b1, acc[1][1]);
      acc[1][2] = MFMA32(a1, b2, acc[1][2]);
      acc[1][3] = MFMA32(a1, b3, acc[1][3]);
    }
  }

  if (hIdx < 20){
    // RMSNorm + RoPE + q0/k0 (+ spatial partial for q), fully in-register.
    const bool isq = hIdx < 16;
    const int h = isq ? hIdx : hIdx - 16;
    const float c = curv[0];
    unsigned short* ob = isq ? qb : kb;
    float* o0p = isq ? q0 : k0;
    // inv_freq for this lane's two freq indices: fi = ml and 16+ml
    const float if0 = __builtin_amdgcn_exp2f((float)ml        * (-13.287712379549449f / 32.f));
    const float if1 = __builtin_amdgcn_exp2f((float)(16 + ml) * (-13.287712379549449f / 32.f));
    float bl = 0.f;
#pragma unroll
    for (int i = 0; i < 2; i++){
#pragma unroll
      for (int r = 0; r < 4; r++){
        const int t = bm + wave * 32 + i * 16 + quad * 4 + r;
        float v0 = acc[i][0][r], v1 = acc[i][1][r], v2 = acc[i][2][r], v3 = acc[i][3][r];
        float ss = v0 * v0 + v1 * v1 + v2 * v2 + v3 * v3;
        ss += __shfl_xor(ss, 1); ss += __shfl_xor(ss, 2);
        ss += __shfl_xor(ss, 4); ss += __shfl_xor(ss, 8);
        float scale = __builtin_amdgcn_rsqf(ss * (1.f / 64.f) + 1e-6f);
        float x0 = v0 * scale, x1 = v1 * scale, x2 = v2 * scale, x3 = v3 * scale;
        float sn0, cs0, sn1, cs1;
        __sincosf((float)t * if0, &sn0, &cs0);
        __sincosf((float)t * if1, &sn1, &cs1);
        unsigned short* op = ob + ((long)h * TT + t) * 64;
        op[ml]      = f2bf( x0 * cs0 + x2 * sn0);
        op[16 + ml] = f2bf( x1 * cs1 + x3 * sn1);
        op[32 + ml] = f2bf( x2 * cs0 - x0 * sn0);
        op[48 + ml] = f2bf( x3 * cs1 - x1 * sn1);
        if (ml == 0){
          float sq = ss * scale * scale;    // |normed|^2, rope preserves norm
          o0p[h * TT + t] = __builtin_amdgcn_sqrtf(1.f / c + sq);
          if (isq) bl += __builtin_amdgcn_sqrtf(sq);
        }
      }
    }
    if (isq && ml == 0) atomicAdd(&bsum, bl);
  } else {
    // V: bf16 + PV-fragment order vt[hk][tile][d][key16], in-register transpose:
    // key16 = quad*4 + r (contiguous per lane) -> one 8B store per (i,j)
    const int hk = hIdx - 20;
#pragma unroll
    for (int i = 0; i < 2; i++){
      const int tile = (bm >> 4) + wave * 2 + i;
#pragma unroll
      for (int j = 0; j < 4; j++){
        uint2 w2 = { pkbf2(acc[i][j][0], acc[i][j][1]), pkbf2(acc[i][j][2], acc[i][j][3]) };
        unsigned short* dst = vt + ((long)(hk * 128 + tile) * 64 + j * 16 + ml) * 16 + quad * 4;
        *(uint2*)dst = w2;
      }
    }
  }
  __syncthreads();
  if (tid == 0) bpart[blockIdx.y * 24 + hIdx] = bsum;
}

// ---------------- 3. head-pair-fused hyperbolic causal attention (unchanged) -------
__global__ __launch_bounds__(256, 3) void attn_kernel(
    const unsigned short* __restrict__ qb_, const unsigned short* __restrict__ kb_,
    const unsigned short* __restrict__ vt_,
    const float* __restrict__ q0_, const float* __restrict__ k0_,
    const float* __restrict__ temp, const float* __restrict__ curv,
    unsigned short* __restrict__ attn_out,
    const float* __restrict__ bpart, float* __restrict__ out_scalar){
  __shared__ float lds[8 * 1104];    // regions: wave (head0), 4+wave (head1)
  const int tid = threadIdx.x, lane = tid & 63, wave = tid >> 6;
  const int qt  = 127 - (blockIdx.x >> 3);     // longest-first
  const int sub = blockIdx.x & 7;
  const int kvh = sub >> 1, hp = sub & 1;
  const int h0 = kvh * 4 + hp * 2, h1 = h0 + 1;
  const int i0 = qt * 16;
  const int ml = lane & 15, quad = lane >> 4;
  const float c = curv[0];
  const float rsc = __builtin_amdgcn_rsqf(c);
  const float fac0 = -rsc / temp[h0];
  const float fac1 = -rsc / temp[h1];
  const f32x4 z = {0.f, 0.f, 0.f, 0.f};
  const unsigned short* kh = kb_ + (long)kvh * TT * 64;
  const unsigned short* vh = vt_ + (long)kvh * 128 * 1024;   // [tile][d][key16]
  const float* k0h = k0_ + kvh * TT;

  short8 qa0 = *(const short8*)&qb_[((long)h0 * TT + i0 + ml) * 64 + quad * 8];
  short8 qa1 = *(const short8*)&qb_[((long)h0 * TT + i0 + ml) * 64 + 32 + quad * 8];
  short8 qb0 = *(const short8*)&qb_[((long)h1 * TT + i0 + ml) * 64 + quad * 8];
  short8 qb1 = *(const short8*)&qb_[((long)h1 * TT + i0 + ml) * 64 + 32 + quad * 8];
  const float q0c0 = c * q0_[h0 * TT + i0 + ml];   // per-lane: q = i0+ml
  const float q0c1 = c * q0_[h1 * TT + i0 + ml];
  const int rowq = i0 + ml;

  f32x4 o0[4], o1[4];
#pragma unroll
  for (int dt = 0; dt < 4; dt++){ o0[dt] = z; o1[dt] = z; }
  float l0 = 0.f, l1 = 0.f;

  const int nt = (i0 + 47) >> 5;   // 32-key tiles

#pragma unroll 1
  for (int t = wave; t < nt; t += 4){
    const int j0 = t << 5;
    const unsigned short* kp = kh + (long)j0 * 64;
    short8 ka0 = *(const short8*)(kp + ml * 64 + quad * 8);
    short8 ka1 = *(const short8*)(kp + ml * 64 + 32 + quad * 8);
    short8 kc0 = *(const short8*)(kp + (16 + ml) * 64 + quad * 8);
    short8 kc1 = *(const short8*)(kp + (16 + ml) * 64 + 32 + quad * 8);
    f32x4 k0a = *(const f32x4*)(k0h + j0 + quad * 4);
    f32x4 k0b = *(const f32x4*)(k0h + j0 + 16 + quad * 4);
    const unsigned short* vpa = vh + (long)(j0 >> 4) * 1024;
    bf16x4 vfa0 = *(const bf16x4*)(vpa + ( 0 + ml) * 16 + quad * 4);
    bf16x4 vfa1 = *(const bf16x4*)(vpa + (16 + ml) * 16 + quad * 4);
    bf16x4 vfa2 = *(const bf16x4*)(vpa + (32 + ml) * 16 + quad * 4);
    bf16x4 vfa3 = *(const bf16x4*)(vpa + (48 + ml) * 16 + quad * 4);
    bf16x4 vfb0 = *(const bf16x4*)(vpa + 1024 + ( 0 + ml) * 16 + quad * 4);
    bf16x4 vfb1 = *(const bf16x4*)(vpa + 1024 + (16 + ml) * 16 + quad * 4);
    bf16x4 vfb2 = *(const bf16x4*)(vpa + 1024 + (32 + ml) * 16 + quad * 4);
    bf16x4 vfb3 = *(const bf16x4*)(vpa + 1024 + (48 + ml) * 16 + quad * 4);

    const int keyb = j0 + quad * 4;
    const bool nm = (j0 + 31 > i0);
    // ---- head 0 ----
    {
      f32x4 s0 = z, s1 = z;
      s0 = MFMA32(ka0, qa0, s0);
      s0 = MFMA32(ka1, qa1, s0);
      s1 = MFMA32(kc0, qa0, s1);
      s1 = MFMA32(kc1, qa1, s1);
      float p0[4], p1[4];
#pragma unroll
      for (int r = 0; r < 4; r++){
        float argA = fmaxf(__builtin_fmaf(-c, s0[r], q0c0 * k0a[r]), 1.00001f);
        float wA   = argA + __builtin_amdgcn_sqrtf(__builtin_fmaf(argA, argA, -1.f));
        float pA   = __builtin_amdgcn_exp2f(fac0 * __builtin_amdgcn_logf(wA));
        float argB = fmaxf(__builtin_fmaf(-c, s1[r], q0c0 * k0b[r]), 1.00001f);
        float wB   = argB + __builtin_amdgcn_sqrtf(__builtin_fmaf(argB, argB, -1.f));
        float pB   = __builtin_amdgcn_exp2f(fac0 * __builtin_amdgcn_logf(wB));
        if (nm){
          if (keyb + r > rowq)      pA = 0.f;
          if (keyb + 16 + r > rowq) pB = 0.f;
        }
        p0[r] = pA; p1[r] = pB;
        l0 += pA + pB;
      }
      uint2 pua = { pkbf2(p0[0], p0[1]), pkbf2(p0[2], p0[3]) };
      uint2 pub = { pkbf2(p1[0], p1[1]), pkbf2(p1[2], p1[3]) };
      bf16x4 pfa = *(bf16x4*)&pua;
      bf16x4 pfb = *(bf16x4*)&pub;
      o0[0] = MFMA16(vfa0, pfa, o0[0]);
      o0[1] = MFMA16(vfa1, pfa, o0[1]);
      o0[2] = MFMA16(vfa2, pfa, o0[2]);
      o0[3] = MFMA16(vfa3, pfa, o0[3]);
      o0[0] = MFMA16(vfb0, pfb, o0[0]);
      o0[1] = MFMA16(vfb1, pfb, o0[1]);
      o0[2] = MFMA16(vfb2, pfb, o0[2]);
      o0[3] = MFMA16(vfb3, pfb, o0[3]);
    }
    // ---- head 1 (same K/V tile) ----
    {
      f32x4 s0 = z, s1 = z;
      s0 = MFMA32(ka0, qb0, s0);
      s0 = MFMA32(ka1, qb1, s0);
      s1 = MFMA32(kc0, qb0, s1);
      s1 = MFMA32(kc1, qb1, s1);
      float p0[4], p1[4];
#pragma unroll
      for (int r = 0; r < 4; r++){
        float argA = fmaxf(__builtin_fmaf(-c, s0[r], q0c1 * k0a[r]), 1.00001f);
        float wA   = argA + __builtin_amdgcn_sqrtf(__builtin_fmaf(argA, argA, -1.f));
        float pA   = __builtin_amdgcn_exp2f(fac1 * __builtin_amdgcn_logf(wA));
        float argB = fmaxf(__builtin_fmaf(-c, s1[r], q0c1 * k0b[r]), 1.00001f);
        float wB   = argB + __builtin_amdgcn_sqrtf(__builtin_fmaf(argB, argB, -1.f));
        float pB   = __builtin_amdgcn_exp2f(fac1 * __builtin_amdgcn_logf(wB));
        if (nm){
          if (keyb + r > rowq)      pA = 0.f;
          if (keyb + 16 + r > rowq) pB = 0.f;
        }
        p0[r] = pA; p1[r] = pB;
        l1 += pA + pB;
      }
      uint2 pua = { pkbf2(p0[0], p0[1]), pkbf2(p0[2], p0[3]) };
      uint2 pub = { pkbf2(p1[0], p1[1]), pkbf2(p1[2], p1[3]) };
      bf16x4 pfa = *(bf16x4*)&pua;
      bf16x4 pfb = *(bf16x4*)&pub;
      o1[0] = MFMA16(vfa0, pfa, o1[0]);
      o1[1] = MFMA16(vfa1, pfa, o1[1]);
      o1[2] = MFMA16(vfa2, pfa, o1[2]);
      o1[3] = MFMA16(vfa3, pfa, o1[3]);
      o1[0] = MFMA16(vfb0, pfb, o1[0]);
      o1[1] = MFMA16(vfb1, pfb, o1[1]);
      o1[2] = MFMA16(vfb2, pfb, o1[2]);
      o1[3] = MFMA16(vfb3, pfb, o1[3]);
    }
  }
  // l across quads (keys split over quads/regs; q=ml fixed)
  l0 += __shfl_xor(l0, 16); l0 += __shfl_xor(l0, 32);
  l1 += __shfl_xor(l1, 16); l1 += __shfl_xor(l1, 32);
  // publish wave partials: O^T reg r -> d = dt*16+quad*4+r at q=ml
  {
    float* w0 = lds + wave * 1104;
    float* w1 = lds + (4 + wave) * 1104;
#pragma unroll
    for (int dt = 0; dt < 4; dt++){
      *(f32x4*)&w0[ml * 68 + dt * 16 + quad * 4] = o0[dt];
      *(f32x4*)&w1[ml * 68 + dt * 16 + quad * 4] = o1[dt];
    }
    if (quad == 0){ w0[1088 + ml] = l0; w1[1088 + ml] = l1; }
  }
  __syncthreads();
  // merge 4 waves per head: thread -> (row = tid>>4, 4 d's)
  {
    const int row = tid >> 4, c0 = (tid & 15) * 4;
#pragma unroll 1
    for (int hb = 0; hb < 2; hb++){
      const float* base = lds + hb * 4 * 1104;
      float L = 0.f; f32x4 s = z;
#pragma unroll
      for (int w = 0; w < 4; w++){
        const float* rg = base + w * 1104;
        L += rg[1088 + row];
        f32x4 t2 = *(const f32x4*)&rg[row * 68 + c0];
        s[0] += t2[0]; s[1] += t2[1]; s[2] += t2[2]; s[3] += t2[3];
      }
      float invL = __builtin_amdgcn_rcpf(L);
      const int h = hb ? h1 : h0;
      uint2 o = { pkbf2(s[0] * invL, s[1] * invL), pkbf2(s[2] * invL, s[3] * invL) };
      *(uint2*)&attn_out[(long)(i0 + row) * 1024 + h * 64 + c0] = o;
    }
  }
  // fused spatial_norm finalize (bpart: 16*24 = 384 entries)
  if (blockIdx.x == 0 && tid < 64){
    float s = 0.f;
    for (int i = lane; i < 384; i += 64) s += bpart[i];
#pragma unroll
    for (int off = 1; off < 64; off <<= 1) s += __shfl_xor(s, off);
    if (lane == 0) out_scalar[0] = s * (1.f / 32768.f);
  }
}

// ---------------- 4. O-proj GEMM, 128m x 64n tiles + 2-phase dbuf ----
// grid dim3(16, 16) = 256 blocks = 1/CU: no inter-block stall overlap, so the
// double-buffer genuinely hides the stage latency here (unlike multi-resident case).
__global__ __launch_bounds__(256) void gemm2_kernel(
    const unsigned short* __restrict__ A, const unsigned short* __restrict__ B,
    float* __restrict__ C){
  __shared__ __align__(16) unsigned short As[2 * 8192];  // [buf][half][128][32] 32 KB
  __shared__ __align__(16) unsigned short Bs[2 * 4096];  // [buf][half][64][32]  16 KB
  const int tid = threadIdx.x, lane = tid & 63, wave = tid >> 6;
  const int bm = blockIdx.y * 128, bn = blockIdx.x * 64;
  const int ml = lane & 15, quad = lane >> 4;
  f32x4 acc[2][4];
  const f32x4 z = {0.f, 0.f, 0.f, 0.f};
#pragma unroll
  for (int i = 0; i < 2; i++)
#pragma unroll
    for (int j = 0; j < 4; j++) acc[i][j] = z;

  const int srow = tid >> 2, scol = (tid & 3) * 8;
  const unsigned short* Ag0 = A + (long)(bm + srow) * 1024 + scol;   // rows 0..63
  const unsigned short* Ag1 = Ag0 + 64 * 1024;                       // rows 64..127
  const unsigned short* Bg  = B + (long)(bn + srow) * 1024 + scol;

#define G2_STAGE(nb, ko)                                                  \
  do {                                                                    \
    gl_lds16(Ag0 + (ko),      As + (nb) * 8192 + wave * 512);             \
    gl_lds16(Ag1 + (ko),      As + (nb) * 8192 + 2048 + wave * 512);      \
    gl_lds16(Ag0 + (ko) + 32, As + (nb) * 8192 + 4096 + wave * 512);      \
    gl_lds16(Ag1 + (ko) + 32, As + (nb) * 8192 + 4096 + 2048 + wave * 512);\
    gl_lds16(Bg  + (ko),      Bs + (nb) * 4096 + wave * 512);             \
    gl_lds16(Bg  + (ko) + 32, Bs + (nb) * 4096 + 2048 + wave * 512);      \
  } while (0)

#define G2_COMPUTE(b)                                                     \
  do {                                                                    \
    _Pragma("unroll")                                                     \
    for (int half = 0; half < 2; half++){                                 \
      const unsigned short* Ah = As + (b) * 8192 + half * 4096;           \
      const unsigned short* Bh = Bs + (b) * 4096 + half * 2048;           \
      short8 a0 = *(const short8*)&Ah[(wave * 32 + ml) * 32 + quad * 8];  \
      short8 a1 = *(const short8*)&Ah[(wave * 32 + 16 + ml) * 32 + quad * 8];\
      short8 b0 = *(const short8*)&Bh[(ml) * 32 + quad * 8];              \
      short8 b1 = *(const short8*)&Bh[(16 + ml) * 32 + quad * 8];         \
      short8 b2 = *(const short8*)&Bh[(32 + ml) * 32 + quad * 8];         \
      short8 b3 = *(const short8*)&Bh[(48 + ml) * 32 + quad * 8];         \
      acc[0][0] = MFMA32(a0, b0, acc[0][0]);                              \
      acc[0][1] = MFMA32(a0, b1, acc[0][1]);                              \
      acc[0][2] = MFMA32(a0, b2, acc[0][2]);                              \
      acc[0][3] = MFMA32(a0, b3, acc[0][3]);                              \
      acc[1][0] = MFMA32(a1, b0, acc[1][0]);                              \
      acc[1][1] = MFMA32(a1, b1, acc[1][1]);                              \
      acc[1][2] = MFMA32(a1, b2, acc[1][2]);                              \
      acc[1][3] = MFMA32(a1, b3, acc[1][3]);                              \
    }                                                                     \
  } while (0)

  G2_STAGE(0, 0);
  __syncthreads();
  for (int kk = 0; kk < 1024; kk += 128){
    G2_STAGE(1, kk + 64);
    G2_COMPUTE(0);
    __syncthreads();
    if (kk + 128 < 1024) G2_STAGE(0, kk + 128);
    G2_COMPUTE(1);
    __syncthreads();
  }
#undef G2_STAGE
#undef G2_COMPUTE

#pragma unroll
  for (int i = 0; i < 2; i++)
#pragma unroll
    for (int j = 0; j < 4; j++)
#pragma unroll
      for (int r = 0; r < 4; r++)
        C[(long)(bm + wave * 32 + i * 16 + quad * 4 + r) * 1024 + bn + j * 16 + ml] = acc[i][j][r];
}

extern "C" void kernel_launch(void* const* d_in, const int* in_sizes, int n_in,
                              void* d_out, int out_size, void* d_ws, size_t ws_size,
                              hipStream_t stream){
  const float* x    = (const float*)d_in[0];
  const float* qw   = (const float*)d_in[1];
  const float* kw   = (const float*)d_in[2];
  const float* vw   = (const float*)d_in[3];
  const float* ow   = (const float*)d_in[4];
  const float* temp = (const float*)d_in[5];
  const float* curv = (const float*)d_in[6];
  float* out = (float*)d_out;

  char* ws = (char*)d_ws;
  size_t off = 0;
  auto alloc = [&](size_t bytes) -> char* {
    char* p = ws + off;
    off += (bytes + 255) & ~(size_t)255;
    return p;
  };
  unsigned short* xb   = (unsigned short*)alloc((size_t)TT * DM * 2);        // 4 MB
  unsigned short* wqkv = (unsigned short*)alloc((size_t)1536 * DM * 2);      // 3 MB
  unsigned short* owb  = (unsigned short*)alloc((size_t)DM * DM * 2);        // 2 MB
  unsigned short* qb   = (unsigned short*)alloc((size_t)NH * TT * HD * 2);   // 4 MB
  unsigned short* kb   = (unsigned short*)alloc((size_t)NKV * TT * HD * 2);  // 1 MB
  unsigned short* vt   = (unsigned short*)alloc((size_t)NKV * TT * HD * 2);  // 1 MB
  float*          q0   = (float*)alloc((size_t)NH * TT * 4);
  float*          k0   = (float*)alloc((size_t)NKV * TT * 4);
  unsigned short* attn = (unsigned short*)alloc((size_t)TT * DM * 2);        // 4 MB
  float*          bpart= (float*)alloc((size_t)768 * 4);

  convertw_kernel<<<4608, 256, 0, stream>>>(x, qw, kw, vw, ow, xb, wqkv, owb);
  gemm1_fused<<<dim3(24, 16), 256, 0, stream>>>(xb, wqkv, qb, kb, vt, q0, k0, bpart, curv);
  attn_kernel<<<1024, 256, 0, stream>>>(qb, kb, vt, q0, k0, temp, curv, attn,
                                        bpart, out + (size_t)TT * DM);
  gemm2_kernel<<<dim3(16, 16), 256, 0, stream>>>(attn, owb, out);
}